// Round 1
// baseline (1205.208 us; speedup 1.0000x reference)
//
#include <hip/hip_runtime.h>
#include <hip/hip_bf16.h>

#define AS1 __attribute__((address_space(1)))
#define AS3 __attribute__((address_space(3)))

typedef __attribute__((ext_vector_type(4))) float  f32x4;
typedef __attribute__((ext_vector_type(8))) __bf16 bf16x8;
typedef __attribute__((ext_vector_type(2))) __bf16 bf16x2;
typedef __attribute__((ext_vector_type(4))) unsigned int uint4_;

static __device__ __forceinline__ unsigned short f2bf_rne(float f) {
    unsigned int u = __builtin_bit_cast(unsigned int, f);
    u += 0x7fffu + ((u >> 16) & 1u);
    return (unsigned short)(u >> 16);
}

static __device__ __forceinline__ unsigned int pack2(float a, float b) {
#if __has_builtin(__builtin_amdgcn_cvt_pk_bf16_f32)
    bf16x2 r = __builtin_amdgcn_cvt_pk_bf16_f32(a, b);
    return __builtin_bit_cast(unsigned int, r);
#else
    return (unsigned int)f2bf_rne(a) | ((unsigned int)f2bf_rne(b) << 16);
#endif
}

// ---------------------------------------------------------------------------
// K0a: convert w_e = attn_w[:, 1024:3072] (1024 x 2048) fp32 -> bf16 bits
// ---------------------------------------------------------------------------
__global__ __launch_bounds__(256) void convwe_kernel(
    const float* __restrict__ attn_w, unsigned short* __restrict__ Bw)
{
    const int idx = (blockIdx.x * 256 + threadIdx.x) * 8;  // < 1024*2048
    const int h = idx >> 11;
    const int e = idx & 2047;
    const float* src = attn_w + h * 3072 + 1024 + e;
    f32x4 v0 = *(const f32x4*)src;
    f32x4 v1 = *(const f32x4*)(src + 4);
    uint4_ o;
    o.x = pack2(v0.x, v0.y); o.y = pack2(v0.z, v0.w);
    o.z = pack2(v1.x, v1.y); o.w = pack2(v1.z, v1.w);
    *(uint4_*)(Bw + idx) = o;
}

// ---------------------------------------------------------------------------
// K0b: hid_proj[b,h] = sum_k hidden[b,k] * attn_w[h,k] + attn_b[h]   (fp32)
// one block per h; attn_w row staged in LDS; 8 b's per wave
// ---------------------------------------------------------------------------
__global__ __launch_bounds__(256) void hidproj_kernel(
    const float* __restrict__ hidden, const float* __restrict__ attn_w,
    const float* __restrict__ attn_b, float* __restrict__ hp)
{
    __shared__ float wrow[1024];
    const int h = blockIdx.x;
    const int t = threadIdx.x;
#pragma unroll
    for (int i = 0; i < 4; ++i) wrow[t + i * 256] = attn_w[h * 3072 + t + i * 256];
    __syncthreads();
    const int wave = t >> 6, lane = t & 63;
    const float bias = attn_b[h];
    for (int b = wave; b < 32; b += 4) {
        float s = 0.f;
#pragma unroll
        for (int j = 0; j < 16; ++j)
            s = fmaf(hidden[b * 1024 + lane + j * 64], wrow[lane + j * 64], s);
#pragma unroll
        for (int off = 1; off < 64; off <<= 1) s += __shfl_xor(s, off);
        if (lane == 0) hp[b * 1024 + h] = s + bias;
    }
}

// ---------------------------------------------------------------------------
// K1: bf16 MFMA GEMM  (M=65536, N=1024, K=2048)  + tanh/v_w epilogue
//     A = enc (fp32, cvt-on-stage), B = w_e bf16 via global_load_lds
//     scores[m] += sum_n v_w[n]*tanh(hp[b,n] + C[m,n])   (atomicAdd partials)
// ---------------------------------------------------------------------------
__global__ __launch_bounds__(256) void gemm_score_kernel(
    const float* __restrict__ A,            // 65536 x 2048 fp32
    const unsigned short* __restrict__ Bw,  // 1024 x 2048 bf16 bits
    const float* __restrict__ hp,           // 32 x 1024 fp32
    const float* __restrict__ vw,           // 1024 fp32
    float* __restrict__ scores)             // 65536 fp32 (pre-zeroed)
{
    __shared__ unsigned short As[128 * 32];
    __shared__ unsigned short Bs[128 * 32];

    // swizzle: 64-block groups = 8 m-tiles x 8 n-tiles; id%8 -> m within group
    // so each XCD (round-robin on id) reuses one A-panel across all 8 n-tiles
    const int id    = blockIdx.x;
    const int group = id >> 6;
    const int lid   = id & 63;
    const int mt    = group * 8 + (lid & 7);   // 0..511
    const int nt    = lid >> 3;                // 0..7
    const long tile_m = (long)mt * 128;
    const int  tile_n = nt * 128;

    const int t    = threadIdx.x;
    const int wave = t >> 6;
    const int lane = t & 63;
    const int quad = lane >> 4;
    const int l15  = lane & 15;

    // --- A staging: thread t covers 16B chunk c=t (rows 0..63) and c=256+t ---
    const int arow = t >> 2;
    const int akc  = (t & 3) * 8;
    const float* aptr0 = A + (tile_m + arow) * 2048 + akc;
    const float* aptr1 = aptr0 + 64 * 2048;
    unsigned short* ad0 = &As[t * 8];
    unsigned short* ad1 = &As[(256 + t) * 8];

    // --- B staging via global_load_lds: wave w covers chunks [w*128, w*128+128) ---
    const int bc0 = wave * 128 + lane;
    const int bc1 = bc0 + 64;
    const unsigned short* bptr0 = Bw + (tile_n + (bc0 >> 2)) * 2048 + (bc0 & 3) * 8;
    const unsigned short* bptr1 = Bw + (tile_n + (bc1 >> 2)) * 2048 + (bc1 & 3) * 8;
    unsigned short* bd0 = &Bs[(wave * 2 + 0) * 512];
    unsigned short* bd1 = &Bs[(wave * 2 + 1) * 512];

    const int wm = (wave >> 1) * 64;
    const int wn = (wave & 1) * 64;

    int aoff[4], boff[4];
#pragma unroll
    for (int i = 0; i < 4; ++i) {
        aoff[i] = (wm + i * 16 + l15) * 32 + quad * 8;
        boff[i] = (wn + i * 16 + l15) * 32 + quad * 8;
    }

    f32x4 acc[4][4];
#pragma unroll
    for (int i = 0; i < 4; ++i)
#pragma unroll
        for (int j = 0; j < 4; ++j) acc[i][j] = (f32x4){0.f, 0.f, 0.f, 0.f};

    // prefetch A for kt=0
    f32x4 av0 = *(const f32x4*)aptr0;
    f32x4 av1 = *(const f32x4*)(aptr0 + 4);
    f32x4 av2 = *(const f32x4*)aptr1;
    f32x4 av3 = *(const f32x4*)(aptr1 + 4);

    for (int kt = 0; kt < 64; ++kt) {
        __syncthreads();  // previous iteration's LDS reads complete
        __builtin_amdgcn_global_load_lds((const AS1 void*)bptr0, (AS3 void*)bd0, 16, 0, 0);
        __builtin_amdgcn_global_load_lds((const AS1 void*)bptr1, (AS3 void*)bd1, 16, 0, 0);
        bptr0 += 32; bptr1 += 32;

        uint4_ w0, w1;
        w0.x = pack2(av0.x, av0.y); w0.y = pack2(av0.z, av0.w);
        w0.z = pack2(av1.x, av1.y); w0.w = pack2(av1.z, av1.w);
        w1.x = pack2(av2.x, av2.y); w1.y = pack2(av2.z, av2.w);
        w1.z = pack2(av3.x, av3.y); w1.w = pack2(av3.z, av3.w);
        *(uint4_*)ad0 = w0;
        *(uint4_*)ad1 = w1;

        if (kt < 63) {  // prefetch next A-tile (overlaps MFMA below)
            aptr0 += 32; aptr1 += 32;
            av0 = *(const f32x4*)aptr0;
            av1 = *(const f32x4*)(aptr0 + 4);
            av2 = *(const f32x4*)aptr1;
            av3 = *(const f32x4*)(aptr1 + 4);
        }
        __syncthreads();  // staging visible (compiler drains vmcnt/lgkmcnt)

        bf16x8 af[4], bfr[4];
#pragma unroll
        for (int i = 0; i < 4; ++i) af[i]  = *(const bf16x8*)(&As[aoff[i]]);
#pragma unroll
        for (int i = 0; i < 4; ++i) bfr[i] = *(const bf16x8*)(&Bs[boff[i]]);
#pragma unroll
        for (int mi = 0; mi < 4; ++mi)
#pragma unroll
            for (int ni = 0; ni < 4; ++ni)
                acc[mi][ni] = __builtin_amdgcn_mfma_f32_16x16x32_bf16(
                    af[mi], bfr[ni], acc[mi][ni], 0, 0, 0);
    }

    // ---- epilogue: score partials ----
    const int bidx = mt >> 4;  // 16 m-tiles per batch
    float vwv[4], hpv[4];
#pragma unroll
    for (int ni = 0; ni < 4; ++ni) {
        const int n = tile_n + wn + ni * 16 + l15;
        vwv[ni] = vw[n];
        hpv[ni] = hp[bidx * 1024 + n];
    }
#pragma unroll
    for (int mi = 0; mi < 4; ++mi) {
#pragma unroll
        for (int r = 0; r < 4; ++r) {
            float s = 0.f;
#pragma unroll
            for (int ni = 0; ni < 4; ++ni) {
                float x = hpv[ni] + acc[mi][ni][r];
                x = fminf(fmaxf(x, -12.f), 12.f);
                const float e  = __expf(x + x);
                const float th = (e - 1.f) * __builtin_amdgcn_rcpf(e + 1.f);
                s = fmaf(vwv[ni], th, s);
            }
            s += __shfl_xor(s, 1);
            s += __shfl_xor(s, 2);
            s += __shfl_xor(s, 4);
            s += __shfl_xor(s, 8);
            if (l15 == 0)
                atomicAdd(&scores[tile_m + wm + mi * 16 + quad * 4 + r], s);
        }
    }
}

// ---------------------------------------------------------------------------
// K2: softmax over S=2048, one block per batch; in-place in d_out attn region
// ---------------------------------------------------------------------------
__global__ __launch_bounds__(256) void softmax_kernel(float* __restrict__ sc)
{
    __shared__ float red[8];
    const int b = blockIdx.x, t = threadIdx.x;
    const int wave = t >> 6, lane = t & 63;
    float* p = sc + b * 2048;
    float v[8];
#pragma unroll
    for (int i = 0; i < 8; ++i) v[i] = p[t + i * 256];
    float m = v[0];
#pragma unroll
    for (int i = 1; i < 8; ++i) m = fmaxf(m, v[i]);
#pragma unroll
    for (int off = 1; off < 64; off <<= 1) m = fmaxf(m, __shfl_xor(m, off));
    if (lane == 0) red[wave] = m;
    __syncthreads();
    m = fmaxf(fmaxf(red[0], red[1]), fmaxf(red[2], red[3]));
    float s = 0.f;
#pragma unroll
    for (int i = 0; i < 8; ++i) { v[i] = __expf(v[i] - m); s += v[i]; }
#pragma unroll
    for (int off = 1; off < 64; off <<= 1) s += __shfl_xor(s, off);
    if (lane == 0) red[4 + wave] = s;
    __syncthreads();
    s = red[4] + red[5] + red[6] + red[7];
    const float inv = 1.0f / s;
#pragma unroll
    for (int i = 0; i < 8; ++i) p[t + i * 256] = v[i] * inv;
}

// ---------------------------------------------------------------------------
// K3: context[b,e] = sum_s attn[b,s] * enc[b,s,e]   (fp32, memory-bound)
// grid = 32 batches x 32 s-chunks of 64; thread owns 8 e-columns; atomicAdd
// ---------------------------------------------------------------------------
__global__ __launch_bounds__(256) void context_kernel(
    const float* __restrict__ enc, const float* __restrict__ attn,
    float* __restrict__ ctx)
{
    const int b  = blockIdx.x >> 5;
    const int sc = blockIdx.x & 31;
    const int t  = threadIdx.x;
    const float* ep = enc + ((long)(b * 2048 + sc * 64)) * 2048 + t * 8;
    const float* ap = attn + b * 2048 + sc * 64;
    f32x4 a0 = (f32x4){0.f, 0.f, 0.f, 0.f};
    f32x4 a1 = (f32x4){0.f, 0.f, 0.f, 0.f};
#pragma unroll 4
    for (int s = 0; s < 64; ++s) {
        const float w = ap[s];
        f32x4 v0 = *(const f32x4*)ep;
        f32x4 v1 = *(const f32x4*)(ep + 4);
        a0 += w * v0;
        a1 += w * v1;
        ep += 2048;
    }
    float* cp = ctx + b * 2048 + t * 8;
    atomicAdd(&cp[0], a0.x); atomicAdd(&cp[1], a0.y);
    atomicAdd(&cp[2], a0.z); atomicAdd(&cp[3], a0.w);
    atomicAdd(&cp[4], a1.x); atomicAdd(&cp[5], a1.y);
    atomicAdd(&cp[6], a1.z); atomicAdd(&cp[7], a1.w);
}

// ---------------------------------------------------------------------------
extern "C" void kernel_launch(void* const* d_in, const int* in_sizes, int n_in,
                              void* d_out, int out_size, void* d_ws, size_t ws_size,
                              hipStream_t stream)
{
    const float* hidden = (const float*)d_in[0];   // 32 x 1024
    const float* enc    = (const float*)d_in[1];   // 32 x 2048 x 2048
    const float* attn_w = (const float*)d_in[2];   // 1024 x 3072
    const float* attn_b = (const float*)d_in[3];   // 1024
    const float* vw     = (const float*)d_in[4];   // 1024
    float* out = (float*)d_out;

    unsigned short* Bw = (unsigned short*)d_ws;                          // 4 MiB
    float* hp = (float*)((char*)d_ws + (size_t)1024 * 2048 * 2);         // 128 KiB

    float* ctx  = out;            // 32 x 2048
    float* attn = out + 65536;    // 32 x 2048 (scores -> weights in place)

    hipMemsetAsync(d_out, 0, (size_t)out_size * 4, stream);
    convwe_kernel <<<1024, 256, 0, stream>>>(attn_w, Bw);
    hidproj_kernel<<<1024, 256, 0, stream>>>(hidden, attn_w, attn_b, hp);
    gemm_score_kernel<<<4096, 256, 0, stream>>>(enc, Bw, hp, vw, attn);
    softmax_kernel<<<32, 256, 0, stream>>>(attn);
    context_kernel<<<1024, 256, 0, stream>>>(enc, attn, ctx);
}

// Round 2
// 1164.434 us; speedup vs baseline: 1.0350x; 1.0350x over previous
//
#include <hip/hip_runtime.h>
#include <hip/hip_bf16.h>

#define AS1 __attribute__((address_space(1)))
#define AS3 __attribute__((address_space(3)))

typedef __attribute__((ext_vector_type(4))) float  f32x4;
typedef __attribute__((ext_vector_type(8))) __bf16 bf16x8;
typedef __attribute__((ext_vector_type(2))) __bf16 bf16x2;
typedef __attribute__((ext_vector_type(4))) unsigned int uint4_;

static __device__ __forceinline__ unsigned short f2bf_rne(float f) {
    unsigned int u = __builtin_bit_cast(unsigned int, f);
    u += 0x7fffu + ((u >> 16) & 1u);
    return (unsigned short)(u >> 16);
}

static __device__ __forceinline__ unsigned int pack2(float a, float b) {
#if __has_builtin(__builtin_amdgcn_cvt_pk_bf16_f32)
    bf16x2 r = __builtin_amdgcn_cvt_pk_bf16_f32(a, b);
    return __builtin_bit_cast(unsigned int, r);
#else
    return (unsigned int)f2bf_rne(a) | ((unsigned int)f2bf_rne(b) << 16);
#endif
}

// ---------------------------------------------------------------------------
// K0a: convert w_e = attn_w[:, 1024:3072] (1024 x 2048) fp32 -> bf16 bits
// ---------------------------------------------------------------------------
__global__ __launch_bounds__(256) void convwe_kernel(
    const float* __restrict__ attn_w, unsigned short* __restrict__ Bw)
{
    const int idx = (blockIdx.x * 256 + threadIdx.x) * 8;  // < 1024*2048
    const int h = idx >> 11;
    const int e = idx & 2047;
    const float* src = attn_w + h * 3072 + 1024 + e;
    f32x4 v0 = *(const f32x4*)src;
    f32x4 v1 = *(const f32x4*)(src + 4);
    uint4_ o;
    o.x = pack2(v0.x, v0.y); o.y = pack2(v0.z, v0.w);
    o.z = pack2(v1.x, v1.y); o.w = pack2(v1.z, v1.w);
    *(uint4_*)(Bw + idx) = o;
}

// ---------------------------------------------------------------------------
// K0c: convert enc (65536 x 2048) fp32 -> bf16 bits (one-shot, pure BW)
// ---------------------------------------------------------------------------
__global__ __launch_bounds__(256) void convenc_kernel(
    const float* __restrict__ enc, unsigned short* __restrict__ dst)
{
    const size_t idx = ((size_t)blockIdx.x * 256 + threadIdx.x) * 8;
    f32x4 v0 = *(const f32x4*)(enc + idx);
    f32x4 v1 = *(const f32x4*)(enc + idx + 4);
    uint4_ o;
    o.x = pack2(v0.x, v0.y); o.y = pack2(v0.z, v0.w);
    o.z = pack2(v1.x, v1.y); o.w = pack2(v1.z, v1.w);
    *(uint4_*)(dst + idx) = o;
}

// ---------------------------------------------------------------------------
// K0b: hid_proj[b,h] = sum_k hidden[b,k] * attn_w[h,k] + attn_b[h]   (fp32)
// ---------------------------------------------------------------------------
__global__ __launch_bounds__(256) void hidproj_kernel(
    const float* __restrict__ hidden, const float* __restrict__ attn_w,
    const float* __restrict__ attn_b, float* __restrict__ hp)
{
    __shared__ float wrow[1024];
    const int h = blockIdx.x;
    const int t = threadIdx.x;
#pragma unroll
    for (int i = 0; i < 4; ++i) wrow[t + i * 256] = attn_w[h * 3072 + t + i * 256];
    __syncthreads();
    const int wave = t >> 6, lane = t & 63;
    const float bias = attn_b[h];
    for (int b = wave; b < 32; b += 4) {
        float s = 0.f;
#pragma unroll
        for (int j = 0; j < 16; ++j)
            s = fmaf(hidden[b * 1024 + lane + j * 64], wrow[lane + j * 64], s);
#pragma unroll
        for (int off = 1; off < 64; off <<= 1) s += __shfl_xor(s, off);
        if (lane == 0) hp[b * 1024 + h] = s + bias;
    }
}

// ---------------------------------------------------------------------------
// K1-fast: bf16 MFMA GEMM (M=65536, N=1024, K=2048), A pre-converted bf16,
// all staging via global_load_lds width=16 (m97 structure), tanh/v_w epilogue.
// ---------------------------------------------------------------------------
__global__ __launch_bounds__(256) void gemm_score_bf16_kernel(
    const unsigned short* __restrict__ Abf,  // 65536 x 2048 bf16 bits
    const unsigned short* __restrict__ Bw,   // 1024 x 2048 bf16 bits
    const float* __restrict__ hp,            // 32 x 1024 fp32
    const float* __restrict__ vw,            // 1024 fp32
    float* __restrict__ scores)              // 65536 fp32 (pre-zeroed)
{
    __shared__ unsigned short As[128 * 32];
    __shared__ unsigned short Bs[128 * 32];

    // swizzle: blocks sharing an A-panel (same mt) land on the same XCD (id%8)
    const int id    = blockIdx.x;
    const int group = id >> 6;
    const int lid   = id & 63;
    const int mt    = group * 8 + (lid & 7);   // 0..511
    const int nt    = lid >> 3;                // 0..7
    const long tile_m = (long)mt * 128;
    const int  tile_n = nt * 128;

    const int t    = threadIdx.x;
    const int wave = t >> 6;
    const int lane = t & 63;
    const int quad = lane >> 4;
    const int l15  = lane & 15;

    // staging chunks: instruction j of wave w covers chunks (j*4+w)*64 + lane
    // chunk c -> row c>>2, 8-elem k-sub (c&3)*8 ; LDS is linear row-major 128x32
    const int ca = wave * 64 + lane;
    const int cb = (4 + wave) * 64 + lane;
    const unsigned short* apg0 = Abf + (tile_m + (ca >> 2)) * 2048 + (ca & 3) * 8;
    const unsigned short* apg1 = Abf + (tile_m + (cb >> 2)) * 2048 + (cb & 3) * 8;
    const unsigned short* bpg0 = Bw + (size_t)(tile_n + (ca >> 2)) * 2048 + (ca & 3) * 8;
    const unsigned short* bpg1 = Bw + (size_t)(tile_n + (cb >> 2)) * 2048 + (cb & 3) * 8;
    unsigned short* ald0 = &As[wave * 512];
    unsigned short* ald1 = &As[(4 + wave) * 512];
    unsigned short* bld0 = &Bs[wave * 512];
    unsigned short* bld1 = &Bs[(4 + wave) * 512];

    const int wm = (wave >> 1) * 64;
    const int wn = (wave & 1) * 64;

    int aoff[4], boff[4];
#pragma unroll
    for (int i = 0; i < 4; ++i) {
        aoff[i] = (wm + i * 16 + l15) * 32 + quad * 8;
        boff[i] = (wn + i * 16 + l15) * 32 + quad * 8;
    }

    f32x4 acc[4][4];
#pragma unroll
    for (int i = 0; i < 4; ++i)
#pragma unroll
        for (int j = 0; j < 4; ++j) acc[i][j] = (f32x4){0.f, 0.f, 0.f, 0.f};

    for (int kt = 0; kt < 64; ++kt) {
        __syncthreads();  // prior LDS reads done before overwrite
        __builtin_amdgcn_global_load_lds((const AS1 void*)apg0, (AS3 void*)ald0, 16, 0, 0);
        __builtin_amdgcn_global_load_lds((const AS1 void*)apg1, (AS3 void*)ald1, 16, 0, 0);
        __builtin_amdgcn_global_load_lds((const AS1 void*)bpg0, (AS3 void*)bld0, 16, 0, 0);
        __builtin_amdgcn_global_load_lds((const AS1 void*)bpg1, (AS3 void*)bld1, 16, 0, 0);
        apg0 += 32; apg1 += 32; bpg0 += 32; bpg1 += 32;
        __syncthreads();  // staging visible

        bf16x8 af[4], bfr[4];
#pragma unroll
        for (int i = 0; i < 4; ++i) af[i]  = *(const bf16x8*)(&As[aoff[i]]);
#pragma unroll
        for (int i = 0; i < 4; ++i) bfr[i] = *(const bf16x8*)(&Bs[boff[i]]);
#pragma unroll
        for (int mi = 0; mi < 4; ++mi)
#pragma unroll
            for (int ni = 0; ni < 4; ++ni)
                acc[mi][ni] = __builtin_amdgcn_mfma_f32_16x16x32_bf16(
                    af[mi], bfr[ni], acc[mi][ni], 0, 0, 0);
    }

    // ---- epilogue: score partials ----
    const int bidx = mt >> 4;
    float vwv[4], hpv[4];
#pragma unroll
    for (int ni = 0; ni < 4; ++ni) {
        const int n = tile_n + wn + ni * 16 + l15;
        vwv[ni] = vw[n];
        hpv[ni] = hp[bidx * 1024 + n];
    }
#pragma unroll
    for (int mi = 0; mi < 4; ++mi) {
#pragma unroll
        for (int r = 0; r < 4; ++r) {
            float s = 0.f;
#pragma unroll
            for (int ni = 0; ni < 4; ++ni) {
                float x = hpv[ni] + acc[mi][ni][r];
                x = fminf(fmaxf(x, -12.f), 12.f);
                const float e  = __expf(x + x);
                const float th = (e - 1.f) * __builtin_amdgcn_rcpf(e + 1.f);
                s = fmaf(vwv[ni], th, s);
            }
            s += __shfl_xor(s, 1);
            s += __shfl_xor(s, 2);
            s += __shfl_xor(s, 4);
            s += __shfl_xor(s, 8);
            if (l15 == 0)
                atomicAdd(&scores[tile_m + wm + mi * 16 + quad * 4 + r], s);
        }
    }
}

// ---------------------------------------------------------------------------
// K1-fallback: previous round's in-kernel-cvt GEMM (used if ws too small)
// ---------------------------------------------------------------------------
__global__ __launch_bounds__(256) void gemm_score_kernel(
    const float* __restrict__ A, const unsigned short* __restrict__ Bw,
    const float* __restrict__ hp, const float* __restrict__ vw,
    float* __restrict__ scores)
{
    __shared__ unsigned short As[128 * 32];
    __shared__ unsigned short Bs[128 * 32];
    const int id    = blockIdx.x;
    const int group = id >> 6;
    const int lid   = id & 63;
    const int mt    = group * 8 + (lid & 7);
    const int nt    = lid >> 3;
    const long tile_m = (long)mt * 128;
    const int  tile_n = nt * 128;
    const int t = threadIdx.x, wave = t >> 6, lane = t & 63;
    const int quad = lane >> 4, l15 = lane & 15;
    const int arow = t >> 2, akc = (t & 3) * 8;
    const float* aptr0 = A + (tile_m + arow) * 2048 + akc;
    const float* aptr1 = aptr0 + 64 * 2048;
    unsigned short* ad0 = &As[t * 8];
    unsigned short* ad1 = &As[(256 + t) * 8];
    const int bc0 = wave * 128 + lane;
    const int bc1 = bc0 + 64;
    const unsigned short* bptr0 = Bw + (tile_n + (bc0 >> 2)) * 2048 + (bc0 & 3) * 8;
    const unsigned short* bptr1 = Bw + (tile_n + (bc1 >> 2)) * 2048 + (bc1 & 3) * 8;
    unsigned short* bd0 = &Bs[(wave * 2 + 0) * 512];
    unsigned short* bd1 = &Bs[(wave * 2 + 1) * 512];
    const int wm = (wave >> 1) * 64, wn = (wave & 1) * 64;
    int aoff[4], boff[4];
#pragma unroll
    for (int i = 0; i < 4; ++i) {
        aoff[i] = (wm + i * 16 + l15) * 32 + quad * 8;
        boff[i] = (wn + i * 16 + l15) * 32 + quad * 8;
    }
    f32x4 acc[4][4];
#pragma unroll
    for (int i = 0; i < 4; ++i)
#pragma unroll
        for (int j = 0; j < 4; ++j) acc[i][j] = (f32x4){0.f, 0.f, 0.f, 0.f};
    f32x4 av0 = *(const f32x4*)aptr0;
    f32x4 av1 = *(const f32x4*)(aptr0 + 4);
    f32x4 av2 = *(const f32x4*)aptr1;
    f32x4 av3 = *(const f32x4*)(aptr1 + 4);
    for (int kt = 0; kt < 64; ++kt) {
        __syncthreads();
        __builtin_amdgcn_global_load_lds((const AS1 void*)bptr0, (AS3 void*)bd0, 16, 0, 0);
        __builtin_amdgcn_global_load_lds((const AS1 void*)bptr1, (AS3 void*)bd1, 16, 0, 0);
        bptr0 += 32; bptr1 += 32;
        uint4_ w0, w1;
        w0.x = pack2(av0.x, av0.y); w0.y = pack2(av0.z, av0.w);
        w0.z = pack2(av1.x, av1.y); w0.w = pack2(av1.z, av1.w);
        w1.x = pack2(av2.x, av2.y); w1.y = pack2(av2.z, av2.w);
        w1.z = pack2(av3.x, av3.y); w1.w = pack2(av3.z, av3.w);
        *(uint4_*)ad0 = w0;
        *(uint4_*)ad1 = w1;
        if (kt < 63) {
            aptr0 += 32; aptr1 += 32;
            av0 = *(const f32x4*)aptr0;
            av1 = *(const f32x4*)(aptr0 + 4);
            av2 = *(const f32x4*)aptr1;
            av3 = *(const f32x4*)(aptr1 + 4);
        }
        __syncthreads();
        bf16x8 af[4], bfr[4];
#pragma unroll
        for (int i = 0; i < 4; ++i) af[i]  = *(const bf16x8*)(&As[aoff[i]]);
#pragma unroll
        for (int i = 0; i < 4; ++i) bfr[i] = *(const bf16x8*)(&Bs[boff[i]]);
#pragma unroll
        for (int mi = 0; mi < 4; ++mi)
#pragma unroll
            for (int ni = 0; ni < 4; ++ni)
                acc[mi][ni] = __builtin_amdgcn_mfma_f32_16x16x32_bf16(
                    af[mi], bfr[ni], acc[mi][ni], 0, 0, 0);
    }
    const int bidx = mt >> 4;
    float vwv[4], hpv[4];
#pragma unroll
    for (int ni = 0; ni < 4; ++ni) {
        const int n = tile_n + wn + ni * 16 + l15;
        vwv[ni] = vw[n];
        hpv[ni] = hp[bidx * 1024 + n];
    }
#pragma unroll
    for (int mi = 0; mi < 4; ++mi) {
#pragma unroll
        for (int r = 0; r < 4; ++r) {
            float s = 0.f;
#pragma unroll
            for (int ni = 0; ni < 4; ++ni) {
                float x = hpv[ni] + acc[mi][ni][r];
                x = fminf(fmaxf(x, -12.f), 12.f);
                const float e  = __expf(x + x);
                const float th = (e - 1.f) * __builtin_amdgcn_rcpf(e + 1.f);
                s = fmaf(vwv[ni], th, s);
            }
            s += __shfl_xor(s, 1);
            s += __shfl_xor(s, 2);
            s += __shfl_xor(s, 4);
            s += __shfl_xor(s, 8);
            if (l15 == 0)
                atomicAdd(&scores[tile_m + wm + mi * 16 + quad * 4 + r], s);
        }
    }
}

// ---------------------------------------------------------------------------
// K2: softmax over S=2048, one block per batch
// ---------------------------------------------------------------------------
__global__ __launch_bounds__(256) void softmax_kernel(float* __restrict__ sc)
{
    __shared__ float red[8];
    const int b = blockIdx.x, t = threadIdx.x;
    const int wave = t >> 6, lane = t & 63;
    float* p = sc + b * 2048;
    float v[8];
#pragma unroll
    for (int i = 0; i < 8; ++i) v[i] = p[t + i * 256];
    float m = v[0];
#pragma unroll
    for (int i = 1; i < 8; ++i) m = fmaxf(m, v[i]);
#pragma unroll
    for (int off = 1; off < 64; off <<= 1) m = fmaxf(m, __shfl_xor(m, off));
    if (lane == 0) red[wave] = m;
    __syncthreads();
    m = fmaxf(fmaxf(red[0], red[1]), fmaxf(red[2], red[3]));
    float s = 0.f;
#pragma unroll
    for (int i = 0; i < 8; ++i) { v[i] = __expf(v[i] - m); s += v[i]; }
#pragma unroll
    for (int off = 1; off < 64; off <<= 1) s += __shfl_xor(s, off);
    if (lane == 0) red[4 + wave] = s;
    __syncthreads();
    s = red[4] + red[5] + red[6] + red[7];
    const float inv = 1.0f / s;
#pragma unroll
    for (int i = 0; i < 8; ++i) p[t + i * 256] = v[i] * inv;
}

// ---------------------------------------------------------------------------
// K3-fast: context partials — block (b, sc) owns 128 s-rows, plain stores
// ---------------------------------------------------------------------------
__global__ __launch_bounds__(256) void context_part_kernel(
    const float* __restrict__ enc, const float* __restrict__ attn,
    float* __restrict__ part)
{
    const int b  = blockIdx.x >> 4;   // 32 batches
    const int sc = blockIdx.x & 15;   // 16 chunks of 128 rows
    const int t  = threadIdx.x;
    const float* ep = enc + ((size_t)(b * 2048 + sc * 128)) * 2048 + t * 8;
    const float* ap = attn + b * 2048 + sc * 128;
    f32x4 a0 = (f32x4){0.f, 0.f, 0.f, 0.f};
    f32x4 a1 = (f32x4){0.f, 0.f, 0.f, 0.f};
#pragma unroll 4
    for (int s = 0; s < 128; ++s) {
        const float w = ap[s];
        f32x4 v0 = *(const f32x4*)ep;
        f32x4 v1 = *(const f32x4*)(ep + 4);
        a0 += w * v0;
        a1 += w * v1;
        ep += 2048;
    }
    float* pp = part + ((size_t)(b * 16 + sc)) * 2048 + t * 8;
    *(f32x4*)pp = a0;
    *(f32x4*)(pp + 4) = a1;
}

__global__ __launch_bounds__(256) void context_reduce_kernel(
    const float* __restrict__ part, float* __restrict__ ctx)
{
    const int idx = blockIdx.x * 256 + threadIdx.x;  // 65536 = b*2048 + e
    const int b = idx >> 11, e = idx & 2047;
    const float* pp = part + ((size_t)b * 16) * 2048 + e;
    float s = 0.f;
#pragma unroll
    for (int i = 0; i < 16; ++i) s += pp[i * 2048];
    ctx[idx] = s;
}

// ---------------------------------------------------------------------------
// K3-fallback: atomic context (used only if ws can't hold partials)
// ---------------------------------------------------------------------------
__global__ __launch_bounds__(256) void context_kernel(
    const float* __restrict__ enc, const float* __restrict__ attn,
    float* __restrict__ ctx)
{
    const int b  = blockIdx.x >> 5;
    const int sc = blockIdx.x & 31;
    const int t  = threadIdx.x;
    const float* ep = enc + ((long)(b * 2048 + sc * 64)) * 2048 + t * 8;
    const float* ap = attn + b * 2048 + sc * 64;
    f32x4 a0 = (f32x4){0.f, 0.f, 0.f, 0.f};
    f32x4 a1 = (f32x4){0.f, 0.f, 0.f, 0.f};
#pragma unroll 4
    for (int s = 0; s < 64; ++s) {
        const float w = ap[s];
        f32x4 v0 = *(const f32x4*)ep;
        f32x4 v1 = *(const f32x4*)(ep + 4);
        a0 += w * v0;
        a1 += w * v1;
        ep += 2048;
    }
    float* cp = ctx + b * 2048 + t * 8;
    atomicAdd(&cp[0], a0.x); atomicAdd(&cp[1], a0.y);
    atomicAdd(&cp[2], a0.z); atomicAdd(&cp[3], a0.w);
    atomicAdd(&cp[4], a1.x); atomicAdd(&cp[5], a1.y);
    atomicAdd(&cp[6], a1.z); atomicAdd(&cp[7], a1.w);
}

// ---------------------------------------------------------------------------
extern "C" void kernel_launch(void* const* d_in, const int* in_sizes, int n_in,
                              void* d_out, int out_size, void* d_ws, size_t ws_size,
                              hipStream_t stream)
{
    const float* hidden = (const float*)d_in[0];   // 32 x 1024
    const float* enc    = (const float*)d_in[1];   // 32 x 2048 x 2048
    const float* attn_w = (const float*)d_in[2];   // 1024 x 3072
    const float* attn_b = (const float*)d_in[3];   // 1024
    const float* vw     = (const float*)d_in[4];   // 1024
    float* out = (float*)d_out;

    // ws layout: [Bw 4MiB][hp 128KiB][part 4MiB][encbf 256MiB]
    const size_t off_Bw   = 0;
    const size_t off_hp   = (size_t)1024 * 2048 * 2;          // 4 MiB
    const size_t off_part = off_hp + (size_t)32 * 1024 * 4;   // +128 KiB
    const size_t off_enc  = off_part + (size_t)512 * 2048 * 4;// +4 MiB
    const size_t need_part = off_enc;
    const size_t need_full = off_enc + (size_t)65536 * 2048 * 2;

    unsigned short* Bw   = (unsigned short*)((char*)d_ws + off_Bw);
    float*          hp   = (float*)((char*)d_ws + off_hp);
    float*          part = (float*)((char*)d_ws + off_part);
    unsigned short* encbf= (unsigned short*)((char*)d_ws + off_enc);

    float* ctx  = out;            // 32 x 2048
    float* attn = out + 65536;    // 32 x 2048 (scores -> weights in place)

    hipMemsetAsync(d_out, 0, (size_t)out_size * 4, stream);
    convwe_kernel <<<1024, 256, 0, stream>>>(attn_w, Bw);
    hidproj_kernel<<<1024, 256, 0, stream>>>(hidden, attn_w, attn_b, hp);

    if (ws_size >= need_full) {
        convenc_kernel<<<65536, 256, 0, stream>>>(enc, encbf);
        gemm_score_bf16_kernel<<<4096, 256, 0, stream>>>(encbf, Bw, hp, vw, attn);
    } else {
        gemm_score_kernel<<<4096, 256, 0, stream>>>(enc, Bw, hp, vw, attn);
    }

    softmax_kernel<<<32, 256, 0, stream>>>(attn);

    if (ws_size >= need_part) {
        context_part_kernel  <<<512, 256, 0, stream>>>(enc, attn, part);
        context_reduce_kernel<<<256, 256, 0, stream>>>(part, ctx);
    } else {
        context_kernel<<<1024, 256, 0, stream>>>(enc, attn, ctx);
    }
}